// Round 1
// 234.371 us; speedup vs baseline: 1.0637x; 1.0637x over previous
//
#include <hip/hip_runtime.h>
#include <math.h>

#define N_NODES 100000
#define N_EDGES 1600000
#define IN_F 128
#define H_F 64

#define NBKT 391     // ceil(100000/256) buckets of 256 nodes
#define BSEG 5120    // per-bucket segment capacity (mean 4092, +16 sigma)
#define BCAP 5120    // LDS staging capacity for adj per bucket (20KB)

// workspace layout in 4-byte words (~46.5 MB total)
#define NP        100096
#define OFF_CNT   0                           // int[512]
#define OFF_MPK   512                         // ushort[12288] packed bf16 Mcat
#define OFF_W1H   6656                        // ushort[8192] W1 hi, B-frag order
#define OFF_W1L   10752                       // ushort[8192] W1 lo
#define OFF_W2H   14848                       // ushort[4096] W2 hi
#define OFF_W2L   16896                       // ushort[4096] W2 lo
#define OFF_OFFS  18944                       // int[N+1]
#define OFF_D2    (OFF_OFFS + NP + 64)        // float[NP]
#define OFF_RD    (OFF_D2 + NP)               // float[NP]
#define OFF_DINV  (OFF_RD + NP)               // float[NP]
#define OFF_ADJ   (OFF_DINV + NP)             // int[N_EDGES]
#define OFF_H0    (OFF_ADJ + N_EDGES)         // ushort[N*64] bf16 gs0
#define OFF_H1    (OFF_H0 + N_NODES*32)       // ushort[N*64] bf16 gs1; binned aliases H1+H2
#define OFF_H2    (OFF_H1 + N_NODES*32)       // ushort[N*64] bf16 gs2

typedef __attribute__((ext_vector_type(8))) short bf16x8;
typedef __attribute__((ext_vector_type(4))) float f32x4;
typedef __attribute__((ext_vector_type(2))) float f32x2;

__device__ __forceinline__ unsigned short bf16rn(float f) {
    unsigned u = __float_as_uint(f);
    u += 0x7FFFu + ((u >> 16) & 1u);
    return (unsigned short)(u >> 16);
}
#define UNPK(u, lo, hi) { lo = __uint_as_float((u) << 16); hi = __uint_as_float((u) & 0xFFFF0000u); }
// accumulate one packed-uint (2 bf16 feats) into a float2 accumulator
#define ACC2(u, A) { f32x2 t_; t_.x = __uint_as_float((u) << 16); \
                     t_.y = __uint_as_float((u) & 0xFFFF0000u); A += t_; }

// ---- prep: zero cnt; pack Mcat + split-bf16 W1/W2 B-fragments ----
__global__ __launch_bounds__(256) void k_prep(const float* __restrict__ Wm1,
        const float* __restrict__ W1, const float* __restrict__ W2,
        unsigned short* __restrict__ mpk,
        unsigned short* __restrict__ w1h, unsigned short* __restrict__ w1l,
        unsigned short* __restrict__ w2h, unsigned short* __restrict__ w2l,
        int* __restrict__ cnt) {
    int idx = blockIdx.x * 256 + threadIdx.x;
    if (idx < 512) cnt[idx] = 0;
    if (idx < 12288) {
        int j = idx & 7;
        int n = (idx >> 3) & 63;
        int qd = (idx >> 9) & 3;
        int s = idx >> 11;
        int k = s * 32 + qd * 8 + j;
        int p = k >> 6;
        int kk = k & 63;
        float w0 = Wm1[kk * 64 + n];
        float w1 = Wm1[(64 + kk) * 64 + n];
        float w2 = Wm1[(128 + kk) * 64 + n];
        float v;
        if (p == 0)      v = 3.0f * w0;
        else if (p == 1) v = 3.0f * (w1 - w0);
        else             v = 0.75f * (w0 + w2) - 1.5f * w1;
        mpk[idx] = bf16rn(v);
    } else if (idx < 12288 + 8192) {
        int lin = idx - 12288;
        int j = lin & 7, cc = (lin >> 3) & 15, ot = (lin >> 7) & 3;
        int qd = (lin >> 9) & 3, ks = lin >> 11;
        float v = W1[(ks * 32 + qd * 8 + j) * 64 + ot * 16 + cc];
        unsigned short h = bf16rn(v);
        w1h[lin] = h;
        w1l[lin] = bf16rn(v - __uint_as_float((unsigned)h << 16));
    } else if (idx < 24576) {
        int lin = idx - 20480;
        int j = lin & 7, cc = (lin >> 3) & 15, ot = (lin >> 7) & 3;
        int qd = (lin >> 9) & 3, ks = lin >> 11;
        float v = W2[(ks * 32 + qd * 8 + j) * 64 + ot * 16 + cc];
        unsigned short h = bf16rn(v);
        w2h[lin] = h;
        w2l[lin] = bf16rn(v - __uint_as_float((unsigned)h << 16));
    }
}

// ---- pass A: bin edges by dst>>8. 8192 edges/block so each bucket gets ~21
// contiguous entries per block -> whole-line writes (write amp ~1.3x).
__global__ __launch_bounds__(256) void k_bin(const int* __restrict__ src,
        const int* __restrict__ dst, int* __restrict__ cnt,
        int* __restrict__ binned, int E) {
    __shared__ int hist[4][NBKT + 1];
    __shared__ int cur4[4][NBKT + 1];
    int t = threadIdx.x;
    int w = t >> 6;
    for (int i = t; i < 4 * (NBKT + 1); i += 256) (&hist[0][0])[i] = 0;
    __syncthreads();
    int base = blockIdx.x * 8192 + t;
    int d[32];
    #pragma unroll
    for (int i = 0; i < 32; ++i) {
        int e = base + i * 256;
        int dd = (e < E) ? dst[e] : -1;
        d[i] = dd;
        if (dd >= 0) atomicAdd(&hist[w][dd >> 8], 1);
    }
    __syncthreads();
    for (int i = t; i < NBKT; i += 256) {
        int h0 = hist[0][i], h1 = hist[1][i], h2 = hist[2][i], h3 = hist[3][i];
        int tot = h0 + h1 + h2 + h3;
        int b0 = (tot > 0) ? atomicAdd(&cnt[i], tot) : 0;
        cur4[0][i] = b0;
        cur4[1][i] = b0 + h0;
        cur4[2][i] = b0 + h0 + h1;
        cur4[3][i] = b0 + h0 + h1 + h2;
    }
    __syncthreads();
    #pragma unroll
    for (int i = 0; i < 32; ++i) {
        int e = base + i * 256;
        if (e < E) {
            int s = src[e];
            int dd = d[i];
            int b = dd >> 8;
            int p = atomicAdd(&cur4[w][b], 1);
            if (p < BSEG) binned[b * BSEG + p] = ((dd & 255) << 17) | s;
        }
    }
}

// ---- pass B: per-bucket CSR fill (256 nodes/bucket) ----
// adj now stores BYTE offsets (src*128) so k_prop's gather needs no 64-bit math.
__global__ __launch_bounds__(256) void k_cfill(const int* __restrict__ binned,
        const int* __restrict__ cnt, int* __restrict__ offs, int* __restrict__ adj,
        float* __restrict__ d2a, float* __restrict__ rda, float* __restrict__ dinva) {
    __shared__ int csum[256];
    __shared__ int degl[256];
    __shared__ int curl[256];
    __shared__ int wsum[4];
    __shared__ int adjl[BCAP];
    int b = blockIdx.x, t = threadIdx.x;
    int p = 0;
    if (2 * t < NBKT) p += cnt[2 * t];
    if (2 * t + 1 < NBKT) p += cnt[2 * t + 1];
    csum[t] = p;
    __syncthreads();
    #pragma unroll
    for (int off = 1; off < 256; off <<= 1) {
        int u = (t >= off) ? csum[t - off] : 0;
        __syncthreads();
        csum[t] += u;
        __syncthreads();
    }
    int b2 = b >> 1;
    int baseb = ((b2 > 0) ? csum[b2 - 1] : 0) + ((b & 1) ? cnt[b - 1] : 0);
    int cntb = cnt[b];
    if (b == 0 && t == 0) offs[N_NODES] = N_EDGES;
    int n0 = b << 8;
    const int* bp = binned + b * BSEG;
    degl[t] = 0;
    __syncthreads();
    for (int i = t; i < cntb; i += 256) atomicAdd(&degl[bp[i] >> 17], 1);
    __syncthreads();
    int d0 = degl[t];
    int lane = t & 63, wid = t >> 6;
    int inc = d0;
    #pragma unroll
    for (int off = 1; off < 64; off <<= 1) {
        int v = __shfl_up(inc, off, 64);
        if (lane >= off) inc += v;
    }
    if (lane == 63) wsum[wid] = inc;
    __syncthreads();
    int wb = 0;
    for (int w = 0; w < wid; ++w) wb += wsum[w];
    int excl = wb + inc - d0;
    curl[t] = excl;
    int n = n0 + t;
    if (n < N_NODES) {
        offs[n] = baseb + excl;
        float df = (float)d0;
        if (df < 1.f) df = 1.f;
        float di = 1.0f / sqrtf(df);
        dinva[n] = di;
        d2a[n] = di * di;
        rda[n] = sqrtf(df);
    }
    __syncthreads();
    for (int i = t; i < cntb; i += 256) {
        int w = bp[i];
        int loc = w >> 17;
        int s = w & 0x1FFFF;
        int pp = atomicAdd(&curl[loc], 1);
        if (pp < BCAP) adjl[pp] = s;
        else adj[baseb + pp] = s << 7;
    }
    __syncthreads();
    int lim = cntb < BCAP ? cntb : BCAP;
    for (int i = t; i < lim; i += 256) adj[baseb + i] = adjl[i] << 7;
}

// ======= fused MLP via split-bf16 MFMA (fp32-accurate) ======================
__global__ __launch_bounds__(256) void k_gemm12(const float* __restrict__ x,
        const unsigned short* __restrict__ w1h, const unsigned short* __restrict__ w1l,
        const unsigned short* __restrict__ w2h, const unsigned short* __restrict__ w2l,
        const float* __restrict__ b1, const float* __restrict__ b2,
        const float* __restrict__ dinva, unsigned short* __restrict__ gsh, int N) {
    __shared__ unsigned int Hl[4][16 * 65];
    __shared__ unsigned short Sl[4][16 * 66];
    int t = threadIdx.x;
    int w = t >> 6, lane = t & 63;
    int c = lane & 15, qd = lane >> 4;
    int nbase = blockIdx.x * 64 + w * 16;
    if (nbase >= N) return;
    int node = nbase + c;
    int nclamp = (node < N) ? node : N - 1;

    f32x4 a0 = {0.f,0.f,0.f,0.f}, a1 = a0, a2 = a0, a3 = a0;
    #pragma unroll
    for (int ks = 0; ks < 4; ++ks) {
        const float* xp = x + (size_t)nclamp * IN_F + ks * 32 + qd * 8;
        float4 xa = *(const float4*)xp;
        float4 xb = *(const float4*)(xp + 4);
        float xs[8] = {xa.x, xa.y, xa.z, xa.w, xb.x, xb.y, xb.z, xb.w};
        bf16x8 ahi, alo;
        #pragma unroll
        for (int j = 0; j < 8; ++j) {
            unsigned short h = bf16rn(xs[j]);
            ahi[j] = (short)h;
            alo[j] = (short)bf16rn(xs[j] - __uint_as_float((unsigned)h << 16));
        }
        const unsigned short* bh = w1h + (size_t)(ks * 4 + qd) * 512;
        const unsigned short* bl = w1l + (size_t)(ks * 4 + qd) * 512;
        bf16x8 h0 = *(const bf16x8*)(bh + 0 * 128 + c * 8);
        bf16x8 l0 = *(const bf16x8*)(bl + 0 * 128 + c * 8);
        bf16x8 h1 = *(const bf16x8*)(bh + 1 * 128 + c * 8);
        bf16x8 l1 = *(const bf16x8*)(bl + 1 * 128 + c * 8);
        bf16x8 h2 = *(const bf16x8*)(bh + 2 * 128 + c * 8);
        bf16x8 l2 = *(const bf16x8*)(bl + 2 * 128 + c * 8);
        bf16x8 h3 = *(const bf16x8*)(bh + 3 * 128 + c * 8);
        bf16x8 l3 = *(const bf16x8*)(bl + 3 * 128 + c * 8);
        a0 = __builtin_amdgcn_mfma_f32_16x16x32_bf16(ahi, h0, a0, 0, 0, 0);
        a1 = __builtin_amdgcn_mfma_f32_16x16x32_bf16(ahi, h1, a1, 0, 0, 0);
        a2 = __builtin_amdgcn_mfma_f32_16x16x32_bf16(ahi, h2, a2, 0, 0, 0);
        a3 = __builtin_amdgcn_mfma_f32_16x16x32_bf16(ahi, h3, a3, 0, 0, 0);
        a0 = __builtin_amdgcn_mfma_f32_16x16x32_bf16(alo, h0, a0, 0, 0, 0);
        a1 = __builtin_amdgcn_mfma_f32_16x16x32_bf16(alo, h1, a1, 0, 0, 0);
        a2 = __builtin_amdgcn_mfma_f32_16x16x32_bf16(alo, h2, a2, 0, 0, 0);
        a3 = __builtin_amdgcn_mfma_f32_16x16x32_bf16(alo, h3, a3, 0, 0, 0);
        a0 = __builtin_amdgcn_mfma_f32_16x16x32_bf16(ahi, l0, a0, 0, 0, 0);
        a1 = __builtin_amdgcn_mfma_f32_16x16x32_bf16(ahi, l1, a1, 0, 0, 0);
        a2 = __builtin_amdgcn_mfma_f32_16x16x32_bf16(ahi, l2, a2, 0, 0, 0);
        a3 = __builtin_amdgcn_mfma_f32_16x16x32_bf16(ahi, l3, a3, 0, 0, 0);
    }
    #pragma unroll
    for (int ot = 0; ot < 4; ++ot) {
        float bb = b1[ot * 16 + c];
        f32x4 a = (ot == 0) ? a0 : (ot == 1) ? a1 : (ot == 2) ? a2 : a3;
        #pragma unroll
        for (int r = 0; r < 4; ++r) {
            float h = fmaxf(a[r] + bb, 0.f);
            unsigned short hh = bf16rn(h);
            unsigned short hl = bf16rn(h - __uint_as_float((unsigned)hh << 16));
            Hl[w][(qd * 4 + r) * 65 + ot * 16 + c] = ((unsigned)hh << 16) | hl;
        }
    }
    f32x4 d0 = {0.f,0.f,0.f,0.f}, d1 = d0, d2 = d0, d3 = d0;
    #pragma unroll
    for (int ks = 0; ks < 2; ++ks) {
        bf16x8 ahi, alo;
        #pragma unroll
        for (int j = 0; j < 8; ++j) {
            unsigned v = Hl[w][c * 65 + ks * 32 + qd * 8 + j];
            ahi[j] = (short)(v >> 16);
            alo[j] = (short)(v & 0xFFFFu);
        }
        const unsigned short* bh = w2h + (size_t)(ks * 4 + qd) * 512;
        const unsigned short* bl = w2l + (size_t)(ks * 4 + qd) * 512;
        bf16x8 h0 = *(const bf16x8*)(bh + 0 * 128 + c * 8);
        bf16x8 l0 = *(const bf16x8*)(bl + 0 * 128 + c * 8);
        bf16x8 h1 = *(const bf16x8*)(bh + 1 * 128 + c * 8);
        bf16x8 l1 = *(const bf16x8*)(bl + 1 * 128 + c * 8);
        bf16x8 h2 = *(const bf16x8*)(bh + 2 * 128 + c * 8);
        bf16x8 l2 = *(const bf16x8*)(bl + 2 * 128 + c * 8);
        bf16x8 h3 = *(const bf16x8*)(bh + 3 * 128 + c * 8);
        bf16x8 l3 = *(const bf16x8*)(bl + 3 * 128 + c * 8);
        d0 = __builtin_amdgcn_mfma_f32_16x16x32_bf16(ahi, h0, d0, 0, 0, 0);
        d1 = __builtin_amdgcn_mfma_f32_16x16x32_bf16(ahi, h1, d1, 0, 0, 0);
        d2 = __builtin_amdgcn_mfma_f32_16x16x32_bf16(ahi, h2, d2, 0, 0, 0);
        d3 = __builtin_amdgcn_mfma_f32_16x16x32_bf16(ahi, h3, d3, 0, 0, 0);
        d0 = __builtin_amdgcn_mfma_f32_16x16x32_bf16(alo, h0, d0, 0, 0, 0);
        d1 = __builtin_amdgcn_mfma_f32_16x16x32_bf16(alo, h1, d1, 0, 0, 0);
        d2 = __builtin_amdgcn_mfma_f32_16x16x32_bf16(alo, h2, d2, 0, 0, 0);
        d3 = __builtin_amdgcn_mfma_f32_16x16x32_bf16(alo, h3, d3, 0, 0, 0);
        d0 = __builtin_amdgcn_mfma_f32_16x16x32_bf16(ahi, l0, d0, 0, 0, 0);
        d1 = __builtin_amdgcn_mfma_f32_16x16x32_bf16(ahi, l1, d1, 0, 0, 0);
        d2 = __builtin_amdgcn_mfma_f32_16x16x32_bf16(ahi, l2, d2, 0, 0, 0);
        d3 = __builtin_amdgcn_mfma_f32_16x16x32_bf16(ahi, l3, d3, 0, 0, 0);
    }
    #pragma unroll
    for (int ot = 0; ot < 4; ++ot) {
        float bb = b2[ot * 16 + c];
        f32x4 a = (ot == 0) ? d0 : (ot == 1) ? d1 : (ot == 2) ? d2 : d3;
        #pragma unroll
        for (int r = 0; r < 4; ++r) {
            int nd = nbase + qd * 4 + r;
            float di = dinva[(nd < N) ? nd : N - 1];
            Sl[w][(qd * 4 + r) * 66 + ot * 16 + c] = bf16rn(di * fmaxf(a[r] + bb, 0.f));
        }
    }
    #pragma unroll
    for (int i = 0; i < 4; ++i) {
        int nl = i * 4 + qd;
        int nd = nbase + nl;
        if (nd < N) {
            ushort4 v;
            v.x = Sl[w][nl * 66 + c * 4 + 0];
            v.y = Sl[w][nl * 66 + c * 4 + 1];
            v.z = Sl[w][nl * 66 + c * 4 + 2];
            v.w = Sl[w][nl * 66 + c * 4 + 3];
            *(ushort4*)(gsh + (size_t)nd * 64 + c * 4) = v;
        }
    }
}

// ---- propagation (bf16 -> bf16) ----
// 16 lanes per node: 2 edge-subgroups (g) x 8 feature-lanes (q).
// Single shfl_xor(8) reduce; adj prefetched one iter ahead of its feature load;
// adj holds byte offsets so the gather is sgpr-base + 32-bit voffset.
__global__ __launch_bounds__(256) void k_prop(const unsigned short* __restrict__ gh,
        unsigned short* __restrict__ gout, const int* __restrict__ offs,
        const int* __restrict__ adjb, const float* __restrict__ d2a, int N) {
    int t = threadIdx.x;
    int lane = t & 63;
    int q = lane & 7;            // which 16B chunk of the 128B row
    int g = (lane >> 3) & 1;     // edge-parity subgroup
    int n = blockIdx.x * 16 + (t >> 6) * 4 + (lane >> 4);
    int nc = (n < N) ? n : N - 1;
    int beg = offs[nc], end = offs[nc + 1];
    float d2n = d2a[nc];
    const char* base = (const char*)gh;
    uint4 sv = *(const uint4*)(gh + (size_t)nc * 64 + 8 * q);   // self row (early)
    f32x2 A0 = {0.f, 0.f}, A1 = A0, A2 = A0, A3 = A0;
    unsigned qo = (unsigned)(q << 4);
    int e = beg + g;                       // my edges: e, e+2, e+4, ...
    bool pa0 = e < end;
    bool pa1 = e + 2 < end;
    unsigned off0 = 0, off1 = 0;
    if (pa0) off0 = (unsigned)adjb[e];
    if (pa1) off1 = (unsigned)adjb[e + 2];
    uint4 v0, v1;
    if (pa0) v0 = *(const uint4*)(base + (size_t)(off0 + qo));
    if (pa1) v1 = *(const uint4*)(base + (size_t)(off1 + qo));
    int en = e + 4;
    bool pv = pa1;
    while (pv) {
        bool pa2 = en < end;
        unsigned off2 = 0;
        if (pa2) off2 = (unsigned)adjb[en];      // adj prefetch, consumed next
        ACC2(v0.x, A0); ACC2(v0.y, A1); ACC2(v0.z, A2); ACC2(v0.w, A3);
        v0 = v1;
        pv = pa2;
        if (pv) v1 = *(const uint4*)(base + (size_t)(off2 + qo));
        en += 2;
    }
    if (pa0) { ACC2(v0.x, A0); ACC2(v0.y, A1); ACC2(v0.z, A2); ACC2(v0.w, A3); }
    // combine the two edge-subgroups (partner lane differs in bit 3)
    A0.x += __shfl_xor(A0.x, 8); A0.y += __shfl_xor(A0.y, 8);
    A1.x += __shfl_xor(A1.x, 8); A1.y += __shfl_xor(A1.y, 8);
    A2.x += __shfl_xor(A2.x, 8); A2.y += __shfl_xor(A2.y, 8);
    A3.x += __shfl_xor(A3.x, 8); A3.y += __shfl_xor(A3.y, 8);
    if (g == 0 && n < N) {
        float l, h;
        uint4 r;
        UNPK(sv.x, l, h);
        r.x = ((unsigned)bf16rn(fmaf(-d2n, A0.y, h)) << 16) | bf16rn(fmaf(-d2n, A0.x, l));
        UNPK(sv.y, l, h);
        r.y = ((unsigned)bf16rn(fmaf(-d2n, A1.y, h)) << 16) | bf16rn(fmaf(-d2n, A1.x, l));
        UNPK(sv.z, l, h);
        r.z = ((unsigned)bf16rn(fmaf(-d2n, A2.y, h)) << 16) | bf16rn(fmaf(-d2n, A2.x, l));
        UNPK(sv.w, l, h);
        r.w = ((unsigned)bf16rn(fmaf(-d2n, A3.y, h)) << 16) | bf16rn(fmaf(-d2n, A3.x, l));
        *(uint4*)(gout + (size_t)n * 64 + 8 * q) = r;
    }
}

// ---- MFMA head: wave = 16 nodes x 64 outs, K=192 over 3 bf16 slices ----
__global__ __launch_bounds__(256) void k_final(const unsigned short* __restrict__ g0h,
        const unsigned short* __restrict__ g1h, const unsigned short* __restrict__ g2h,
        const unsigned short* __restrict__ mpk, const float* __restrict__ bm1,
        const float* __restrict__ Wm2, const float* __restrict__ bm2,
        const float* __restrict__ rda, float* __restrict__ out, int N) {
    int t = threadIdx.x;
    int w = t >> 6, lane = t & 63;
    int c = lane & 15, qd = lane >> 4;
    int nbase = blockIdx.x * 64 + w * 16;
    if (nbase >= N) return;
    int node = nbase + c;
    int nclamp = (node < N) ? node : N - 1;
    const unsigned short* bufs[3] = {g0h, g1h, g2h};
    f32x4 acc0 = {0.f, 0.f, 0.f, 0.f};
    f32x4 acc1 = {0.f, 0.f, 0.f, 0.f};
    f32x4 acc2 = {0.f, 0.f, 0.f, 0.f};
    f32x4 acc3 = {0.f, 0.f, 0.f, 0.f};
    #pragma unroll
    for (int s = 0; s < 6; ++s) {
        const unsigned short* gp = bufs[s >> 1];
        int k0 = (s & 1) * 32;
        bf16x8 a = *(const bf16x8*)(gp + (size_t)nclamp * 64 + k0 + qd * 8);
        const unsigned short* mb = mpk + (size_t)((s * 4 + qd) * 64) * 8;
        bf16x8 b0 = *(const bf16x8*)(mb + (size_t)(c) * 8);
        bf16x8 b1 = *(const bf16x8*)(mb + (size_t)(16 + c) * 8);
        bf16x8 b2 = *(const bf16x8*)(mb + (size_t)(32 + c) * 8);
        bf16x8 b3 = *(const bf16x8*)(mb + (size_t)(48 + c) * 8);
        acc0 = __builtin_amdgcn_mfma_f32_16x16x32_bf16(a, b0, acc0, 0, 0, 0);
        acc1 = __builtin_amdgcn_mfma_f32_16x16x32_bf16(a, b1, acc1, 0, 0, 0);
        acc2 = __builtin_amdgcn_mfma_f32_16x16x32_bf16(a, b2, acc2, 0, 0, 0);
        acc3 = __builtin_amdgcn_mfma_f32_16x16x32_bf16(a, b3, acc3, 0, 0, 0);
    }
    float rdr[4];
    #pragma unroll
    for (int r = 0; r < 4; ++r) {
        int nd = nbase + qd * 4 + r;
        rdr[r] = rda[(nd < N) ? nd : N - 1];
    }
    float p0[4] = {0.f, 0.f, 0.f, 0.f};
    float p1[4] = {0.f, 0.f, 0.f, 0.f};
    #pragma unroll
    for (int ot = 0; ot < 4; ++ot) {
        int col = ot * 16 + c;
        float bmc = bm1[col];
        float wc0 = Wm2[col * 2 + 0];
        float wc1 = Wm2[col * 2 + 1];
        f32x4 a = (ot == 0) ? acc0 : (ot == 1) ? acc1 : (ot == 2) ? acc2 : acc3;
        #pragma unroll
        for (int r = 0; r < 4; ++r) {
            float h = fmaxf(fmaf(rdr[r], a[r], bmc), 0.f);
            p0[r] = fmaf(h, wc0, p0[r]);
            p1[r] = fmaf(h, wc1, p1[r]);
        }
    }
    #pragma unroll
    for (int m = 1; m < 16; m <<= 1) {
        #pragma unroll
        for (int r = 0; r < 4; ++r) {
            p0[r] += __shfl_xor(p0[r], m);
            p1[r] += __shfl_xor(p1[r], m);
        }
    }
    if (c == 0) {
        float bo0 = bm2[0], bo1 = bm2[1];
        #pragma unroll
        for (int r = 0; r < 4; ++r) {
            int nd = nbase + qd * 4 + r;
            if (nd < N) {
                float2 o;
                o.x = p0[r] + bo0;
                o.y = p1[r] + bo1;
                *(float2*)(out + (size_t)nd * 2) = o;
            }
        }
    }
}

extern "C" void kernel_launch(void* const* d_in, const int* in_sizes, int n_in,
                              void* d_out, int out_size, void* d_ws, size_t ws_size,
                              hipStream_t stream) {
    const float* x   = (const float*)d_in[0];
    const int*   ei  = (const int*)d_in[1];
    const float* W1  = (const float*)d_in[2];
    const float* b1  = (const float*)d_in[3];
    const float* W2  = (const float*)d_in[4];
    const float* b2  = (const float*)d_in[5];
    const float* Wm1 = (const float*)d_in[6];
    const float* bm1 = (const float*)d_in[7];
    const float* Wm2 = (const float*)d_in[8];
    const float* bm2 = (const float*)d_in[9];
    float* out = (float*)d_out;

    int* ws = (int*)d_ws;
    int*   cnt   = ws + OFF_CNT;
    unsigned short* mpk = (unsigned short*)(ws + OFF_MPK);
    unsigned short* w1h = (unsigned short*)(ws + OFF_W1H);
    unsigned short* w1l = (unsigned short*)(ws + OFF_W1L);
    unsigned short* w2h = (unsigned short*)(ws + OFF_W2H);
    unsigned short* w2l = (unsigned short*)(ws + OFF_W2L);
    int*   offs  = ws + OFF_OFFS;
    float* d2a   = (float*)(ws + OFF_D2);
    float* rda   = (float*)(ws + OFF_RD);
    float* dinva = (float*)(ws + OFF_DINV);
    int*   adj   = ws + OFF_ADJ;
    unsigned short* gs0h = (unsigned short*)(ws + OFF_H0);
    unsigned short* gs1h = (unsigned short*)(ws + OFF_H1);
    unsigned short* gs2h = (unsigned short*)(ws + OFF_H2);
    int*   binned = ws + OFF_H1;   // aliases H1(+H2); dead before prop1 writes gs1h

    const int* srcp = ei;
    const int* dstp = ei + N_EDGES;

    k_prep<<<96, 256, 0, stream>>>(Wm1, W1, W2, mpk, w1h, w1l, w2h, w2l, cnt);
    k_bin<<<(N_EDGES + 8191) / 8192, 256, 0, stream>>>(srcp, dstp, cnt, binned, N_EDGES);
    k_cfill<<<NBKT, 256, 0, stream>>>(binned, cnt, offs, adj, d2a, rda, dinva);

    int nblk = (N_NODES + 63) / 64;
    k_gemm12<<<nblk, 256, 0, stream>>>(x, w1h, w1l, w2h, w2l, b1, b2, dinva, gs0h, N_NODES);

    k_prop<<<(N_NODES + 15) / 16, 256, 0, stream>>>(gs0h, gs1h, offs, adj, d2a, N_NODES);
    k_prop<<<(N_NODES + 15) / 16, 256, 0, stream>>>(gs1h, gs2h, offs, adj, d2a, N_NODES);

    k_final<<<nblk, 256, 0, stream>>>(gs0h, gs1h, gs2h, mpk, bm1, Wm2, bm2, rda, out, N_NODES);
}